// Round 1
// baseline (126.838 us; speedup 1.0000x reference)
//
#include <hip/hip_runtime.h>

#define BSZ 8
#define NQ 2048
#define MP 64
#define DD 1024
#define K2ALL 2048       // interleaved ushort per (b,m) row: [m2, -2*m2*p]
#define BN 16            // query rows per block
#define NSTEP 64         // k-steps (2048 interleaved / 32 per MFMA)
#define NTILES (NQ / BN) // 128
#define LDC 520          // 512 interleaved ushorts per k-chunk + 8 pad

typedef __bf16 bf16x8 __attribute__((ext_vector_type(8)));
typedef float f32x4 __attribute__((ext_vector_type(4)));
typedef unsigned short us8 __attribute__((ext_vector_type(8)));

__device__ __forceinline__ unsigned short f2bf(float f) {
    union { float f; unsigned int u; } v; v.f = f;
    unsigned int u = v.u;
    return (unsigned short)((u + 0x7FFFu + ((u >> 16) & 1u)) >> 16);  // RNE
}

// Pass 1: pack proto/mask -> bf16 [m2, -2*m2*p] in MFMA *fragment order* +
// fp32 pterm. Fragment layout: flat ushort index
//   ((((b*4 + mt)*64 + s)*64) + lane)*8 + e
// where mt=m>>4, s=k32-step, lane=(t&3)*16 + (m&15), e=0..7.
// A wave's per-step B-load in the main kernel is then one contiguous 1 KB.
__global__ __launch_bounds__(256) void pack_kernel(
    const float* __restrict__ proto,
    const float* __restrict__ mask,
    unsigned short* __restrict__ Pf,
    float* __restrict__ Pterm)
{
    const int row = blockIdx.x;          // b*64 + m
    const int m = row & 63;
    const int b = row >> 6;
    const int t = threadIdx.x;           // d-group: d = 4t..4t+3 -> k = 8t..8t+7

    const float4 mk = *(const float4*)(mask  + (size_t)row * DD + 4 * t);
    const float4 pr = *(const float4*)(proto + (size_t)row * DD + 4 * t);

    const float m2x = mk.x * mk.x, m2y = mk.y * mk.y,
                m2z = mk.z * mk.z, m2w = mk.w * mk.w;
    const float ax = mk.x * pr.x, ay = mk.y * pr.y,
                az = mk.z * pr.z, aw = mk.w * pr.w;
    float pacc = ax * ax + ay * ay + az * az + aw * aw;

    us8 o;
    o[0] = f2bf(m2x); o[1] = f2bf(-2.f * m2x * pr.x);
    o[2] = f2bf(m2y); o[3] = f2bf(-2.f * m2y * pr.y);
    o[4] = f2bf(m2z); o[5] = f2bf(-2.f * m2z * pr.z);
    o[6] = f2bf(m2w); o[7] = f2bf(-2.f * m2w * pr.w);

    const int mt   = m >> 4;
    const int s    = t >> 2;                      // k32 step 0..63
    const int lane = (t & 3) * 16 + (m & 15);     // consuming lane
    const size_t idx = ((((size_t)(b * 4 + mt)) * 64 + s) * 64 + lane) * 8;
    *(us8*)(Pf + idx) = o;

    __shared__ float red[4];
    #pragma unroll
    for (int off = 32; off > 0; off >>= 1)
        pacc += __shfl_down(pacc, off, 64);
    const int lane64 = t & 63, w = t >> 6;
    if (lane64 == 0) red[w] = pacc;
    __syncthreads();
    if (t == 0) Pterm[row] = red[0] + red[1] + red[2] + red[3];
}

// Pass 2: 1024 blocks (b = bid&7 -> XCD-affine), 256 threads.
// v2: 4-chunk software pipeline. Per chunk c of 256 d-values:
//   issue global query loads for chunk c+2 (regs)
//   | cvt+LDS-store chunk c+1 (regs from previous issue)
//   | 16 MFMA steps on chunk c (A from LDS, B streamed depth-8 from L2)
// One __syncthreads per chunk publishes c+1. This overlaps the query HBM
// stream with the MFMA/L2 stream instead of serializing them grid-wide.
__global__ __launch_bounds__(256) void proto_main_kernel(
    const float* __restrict__ query,
    const unsigned short* __restrict__ Pf,
    const float* __restrict__ Pterm,
    const float* __restrict__ scale,
    float* __restrict__ out)
{
    __shared__ unsigned short Qs[4][BN][LDC];   // 66.6 KB -> 2 blocks/CU

    const int tid = threadIdx.x;
    const int bid = blockIdx.x;
    const int b  = bid & 7;
    const int n0 = (bid >> 3) * BN;

    const int qrow = tid >> 4;           // 0..15
    const int qc   = tid & 15;
    const float* qptr = query + ((size_t)b * NQ + n0 + qrow) * DD + 4 * qc;

    const int lane = tid & 63;
    const int wid  = tid >> 6;           // m-tile owner
    const int lrow = lane & 15;
    const int lq   = (lane >> 4) * 8;

    const int mcol = 16 * wid + lrow;
    // fragment-packed B: wave base, step stride = 512 ushorts (1 KB)
    const unsigned short* bbase =
        Pf + (((size_t)(b * 4 + wid)) * 64) * 512 + (size_t)lane * 8;

    const float pt = Pterm[b * MP + mcol];
    const float sc = scale[0] * (1.0f / (float)DD);

// chunk C covers d in [256C, 256C+256): thread's 4 float4 at qptr+256C+64pp
#define LOADQ(r0, r1, r2, r3, C)                                         \
    r0 = *(const float4*)(qptr + 256 * (C));                             \
    r1 = *(const float4*)(qptr + 256 * (C) + 64);                        \
    r2 = *(const float4*)(qptr + 256 * (C) + 128);                       \
    r3 = *(const float4*)(qptr + 256 * (C) + 192);

#define CV1(Q, C, PP) {                                                  \
    us8 o;                                                               \
    o[0] = f2bf(Q.x * Q.x); o[1] = f2bf(Q.x);                            \
    o[2] = f2bf(Q.y * Q.y); o[3] = f2bf(Q.y);                            \
    o[4] = f2bf(Q.z * Q.z); o[5] = f2bf(Q.z);                            \
    o[6] = f2bf(Q.w * Q.w); o[7] = f2bf(Q.w);                            \
    *(us8*)(&Qs[C][qrow][8 * qc + 128 * (PP)]) = o; }

#define CV4(r0, r1, r2, r3, C)                                           \
    CV1(r0, C, 0) CV1(r1, C, 1) CV1(r2, C, 2) CV1(r3, C, 3)

// 16 MFMA steps on chunk C; depth-8 contiguous B queue survives barriers
#define MFMA_CHUNK(C)                                                    \
    _Pragma("unroll")                                                    \
    for (int s = 0; s < 16; ++s) {                                       \
        const int t = 16 * (C) + s;                                      \
        const bf16x8 bb = bq[t & 7];                                     \
        if (t + 8 < NSTEP)                                               \
            bq[t & 7] = *(const bf16x8*)(bbase + (size_t)(t + 8) * 512); \
        const bf16x8 a = *(const bf16x8*)(&Qs[C][lrow][32 * s + lq]);    \
        acc = __builtin_amdgcn_mfma_f32_16x16x32_bf16(a, bb, acc, 0, 0, 0); \
    }

    float4 ra0, ra1, ra2, ra3, rb0, rb1, rb2, rb3;
    f32x4 acc = (f32x4){0.f, 0.f, 0.f, 0.f};
    bf16x8 bq[8];

    // prologue: chunks 0,1 in flight, B queue primed, chunk 0 published
    LOADQ(ra0, ra1, ra2, ra3, 0)
    LOADQ(rb0, rb1, rb2, rb3, 1)
    #pragma unroll
    for (int i = 0; i < 8; ++i)
        bq[i] = *(const bf16x8*)(bbase + (size_t)i * 512);
    CV4(ra0, ra1, ra2, ra3, 0)
    __syncthreads();                       // chunk 0 visible

    LOADQ(ra0, ra1, ra2, ra3, 2)           // ra regs free after CV4(.,0)
    CV4(rb0, rb1, rb2, rb3, 1)
    MFMA_CHUNK(0)
    __syncthreads();                       // chunk 1 visible

    LOADQ(rb0, rb1, rb2, rb3, 3)
    CV4(ra0, ra1, ra2, ra3, 2)
    MFMA_CHUNK(1)
    __syncthreads();                       // chunk 2 visible

    CV4(rb0, rb1, rb2, rb3, 3)
    MFMA_CHUNK(2)
    __syncthreads();                       // chunk 3 visible

    MFMA_CHUNK(3)

    // epilogue: n = n0 + (lane>>4)*4 + r, m = mcol
    const size_t ob = ((size_t)b * NQ + (size_t)(n0 + (lane >> 4) * 4)) * MP + mcol;
    #pragma unroll
    for (int r = 0; r < 4; ++r)
        out[ob + (size_t)r * MP] = (acc[r] + pt) * sc;
}

extern "C" void kernel_launch(void* const* d_in, const int* in_sizes, int n_in,
                              void* d_out, int out_size, void* d_ws, size_t ws_size,
                              hipStream_t stream) {
    (void)in_sizes; (void)n_in; (void)ws_size; (void)out_size;
    const float* proto = (const float*)d_in[0];
    const float* mask  = (const float*)d_in[1];
    const float* query = (const float*)d_in[2];
    const float* scale = (const float*)d_in[5];
    float* out = (float*)d_out;

    unsigned short* Pf = (unsigned short*)d_ws;                           // 2 MiB
    float* Pterm = (float*)((char*)d_ws + (size_t)BSZ * MP * K2ALL * 2);  // +2 KiB

    pack_kernel<<<dim3(BSZ * MP), dim3(256), 0, stream>>>(proto, mask, Pf, Pterm);
    proto_main_kernel<<<dim3(BSZ * NTILES), dim3(256), 0, stream>>>(
        query, Pf, Pterm, scale, out);
}